// Round 1
// baseline (195.659 us; speedup 1.0000x reference)
//
#include <hip/hip_runtime.h>

#define BLOCK 256
#define WAVES_PER_BLOCK (BLOCK / 64)

__global__ __launch_bounds__(BLOCK) void LossFun_kernel(
    const float* __restrict__ A,   // embedding_a [B,128]
    const float* __restrict__ P,   // embedding_p [B,128]
    const float* __restrict__ N,   // embedding_n [B,128]
    const float* __restrict__ T,   // triplets_dis [B,2]
    const int*   __restrict__ bidx,// batch_index [B]
    float* __restrict__ out,       // scalar
    int B, float invB)
{
    const int lane  = threadIdx.x & 63;
    const int wid   = threadIdx.x >> 6;
    const int gwave = blockIdx.x * WAVES_PER_BLOCK + wid;
    const int nwav  = gridDim.x * WAVES_PER_BLOCK;

    float acc = 0.f;

    for (int row = gwave; row < B; row += nwav) {
        const size_t base = (size_t)row * 128;
        const float2 a2 = ((const float2*)(A + base))[lane];
        const float2 p2 = ((const float2*)(P + base))[lane];
        const float2 n2 = ((const float2*)(N + base))[lane];

        float dx = a2.x - p2.x, dy = a2.y - p2.y;
        float s_ap = dx * dx + dy * dy;
        dx = a2.x - n2.x; dy = a2.y - n2.y;
        float s_an = dx * dx + dy * dy;

        // 64-lane butterfly reduction of both partial sums
        #pragma unroll
        for (int off = 32; off >= 1; off >>= 1) {
            s_ap += __shfl_xor(s_ap, off);
            s_an += __shfl_xor(s_an, off);
        }

        if (lane == 0) {
            const int    bi = bidx[row];
            const float2 td = ((const float2*)T)[bi];
            const float D_ap = __expf(-td.x);
            const float D_an = __expf(-td.y);
            const float v_ap = __expf(-sqrtf(s_ap));
            const float v_an = __expf(-sqrtf(s_an));
            const float e1 = D_ap - v_ap;
            const float e2 = D_an - v_an;
            acc += D_ap * e1 * e1 + D_an * e2 * e2;
        }
    }

    __shared__ float wacc[WAVES_PER_BLOCK];
    if (lane == 0) wacc[wid] = acc;
    __syncthreads();
    if (threadIdx.x == 0) {
        float s = 0.f;
        #pragma unroll
        for (int i = 0; i < WAVES_PER_BLOCK; ++i) s += wacc[i];
        atomicAdd(out, s * invB);
    }
}

extern "C" void kernel_launch(void* const* d_in, const int* in_sizes, int n_in,
                              void* d_out, int out_size, void* d_ws, size_t ws_size,
                              hipStream_t stream) {
    const float* A    = (const float*)d_in[0];
    const float* P    = (const float*)d_in[1];
    const float* N    = (const float*)d_in[2];
    const float* T    = (const float*)d_in[3];
    const int*   bidx = (const int*)  d_in[4];
    // d_in[5..7] (a_ids, p_ids, n_ids) are unused by the reference.

    const int B = in_sizes[0] / 128;
    float* out = (float*)d_out;

    hipMemsetAsync(out, 0, sizeof(float), stream);

    const int blocks = 2048;   // 8192 waves, grid-stride over 524288 rows
    LossFun_kernel<<<blocks, BLOCK, 0, stream>>>(A, P, N, T, bidx, out, B, 1.0f / (float)B);
}

// Round 2
// 152.367 us; speedup vs baseline: 1.2841x; 1.2841x over previous
//
#include <hip/hip_runtime.h>

#define BLOCK 256
#define WPB (BLOCK / 64)

// v_add_f32 with DPP modifier (compiler fuses update_dpp + add)
template <int CTRL>
__device__ __forceinline__ float dpp_add(float x) {
    int s = __builtin_amdgcn_update_dpp(0, __float_as_int(x), CTRL, 0xf, 0xf, true);
    return x + __int_as_float(s);
}

// Sum over each 32-lane half; result lands in lane 31 (lower half) / lane 63 (upper half).
__device__ __forceinline__ float reduce32(float x) {
    x = dpp_add<0x111>(x);  // row_shr:1
    x = dpp_add<0x112>(x);  // row_shr:2
    x = dpp_add<0x114>(x);  // row_shr:4
    x = dpp_add<0x118>(x);  // row_shr:8  -> lane 15/31/47/63 hold 16-lane sums
    x = dpp_add<0x142>(x);  // row_bcast:15 -> lanes 31/63 hold 32-lane sums
    return x;
}

__global__ __launch_bounds__(BLOCK) void LossFun_kernel(
    const float* __restrict__ A,
    const float* __restrict__ P,
    const float* __restrict__ N,
    const float* __restrict__ T,     // [B,2]
    const int*   __restrict__ bidx,  // [B]
    float* __restrict__ out,
    int B, float invB)
{
    const int lane  = threadIdx.x & 63;
    const int wid   = threadIdx.x >> 6;
    const int gwave = blockIdx.x * WPB + wid;
    const int nwav  = gridDim.x * WPB;
    const int npair = B >> 1;   // 2 rows per wave-iteration

    float acc = 0.f;

    auto body = [&](int pr) {
        const size_t base = (size_t)pr * 256;           // 2 rows x 128 floats
        const float4 a = ((const float4*)(A + base))[lane];
        const float4 p = ((const float4*)(P + base))[lane];
        const float4 n = ((const float4*)(N + base))[lane];

        float d0 = a.x - p.x, d1 = a.y - p.y, d2 = a.z - p.z, d3 = a.w - p.w;
        float sap = d0 * d0 + d1 * d1 + d2 * d2 + d3 * d3;
        d0 = a.x - n.x; d1 = a.y - n.y; d2 = a.z - n.z; d3 = a.w - n.w;
        float san = d0 * d0 + d1 * d1 + d2 * d2 + d3 * d3;

        sap = reduce32(sap);
        san = reduce32(san);

        if ((lane & 31) == 31) {                        // lanes 31 and 63 finish one row each
            const int row = pr * 2 + (lane >> 5);
            const int bi  = bidx[row];
            const float2 td = ((const float2*)T)[bi];
            const float Dap = __expf(-td.x);
            const float Dan = __expf(-td.y);
            const float vap = __expf(-sqrtf(sap));
            const float van = __expf(-sqrtf(san));
            const float e1 = Dap - vap;
            const float e2 = Dan - van;
            acc += Dap * e1 * e1 + Dan * e2 * e2;
        }
    };

    int pr = gwave;
    for (; pr + nwav < npair; pr += 2 * nwav) {         // 2x unroll: independent loads in flight
        body(pr);
        body(pr + nwav);
    }
    for (; pr < npair; pr += nwav) body(pr);

    // acc lives in lanes 31 and 63; one-time wave combine, then block combine.
    acc += __shfl_xor(acc, 32);                          // lane31 <-> lane63
    __shared__ float wacc[WPB];
    if (lane == 31) wacc[wid] = acc;
    __syncthreads();
    if (threadIdx.x == 0) {
        float s = 0.f;
        #pragma unroll
        for (int i = 0; i < WPB; ++i) s += wacc[i];
        atomicAdd(out, s * invB);
    }
}

extern "C" void kernel_launch(void* const* d_in, const int* in_sizes, int n_in,
                              void* d_out, int out_size, void* d_ws, size_t ws_size,
                              hipStream_t stream) {
    const float* A    = (const float*)d_in[0];
    const float* P    = (const float*)d_in[1];
    const float* N    = (const float*)d_in[2];
    const float* T    = (const float*)d_in[3];
    const int*   bidx = (const int*)  d_in[4];

    const int B = in_sizes[0] / 128;
    float* out = (float*)d_out;

    hipMemsetAsync(out, 0, sizeof(float), stream);

    const int blocks = 2048;   // 8 blocks/CU, 8192 waves
    LossFun_kernel<<<blocks, BLOCK, 0, stream>>>(A, P, N, T, bidx, out, B, 1.0f / (float)B);
}

// Round 3
// 146.548 us; speedup vs baseline: 1.3351x; 1.0397x over previous
//
#include <hip/hip_runtime.h>

#define BLOCK 256
#define WPB (BLOCK / 64)

template <int CTRL>
__device__ __forceinline__ float dpp_add(float x) {
    int s = __builtin_amdgcn_update_dpp(0, __float_as_int(x), CTRL, 0xf, 0xf, true);
    return x + __int_as_float(s);
}

// Sum each 32-lane half; 32-lane sums land in lanes 31 and 63.
__device__ __forceinline__ float reduce32(float x) {
    x = dpp_add<0x111>(x);  // row_shr:1
    x = dpp_add<0x112>(x);  // row_shr:2
    x = dpp_add<0x114>(x);  // row_shr:4
    x = dpp_add<0x118>(x);  // row_shr:8
    x = dpp_add<0x142>(x);  // row_bcast:15
    return x;
}

struct Frag { float4 a0, a1, p0, p1, n0, n1; };

__global__ __launch_bounds__(BLOCK) void LossFun_kernel(
    const float* __restrict__ A,
    const float* __restrict__ P,
    const float* __restrict__ N,
    const float* __restrict__ T,     // [B,2]
    const int*   __restrict__ bidx,  // [B]
    float* __restrict__ out,
    int B, float invB)
{
    const int lane  = threadIdx.x & 63;
    const int wid   = threadIdx.x >> 6;
    const int gwave = blockIdx.x * WPB + wid;
    const int nwav  = gridDim.x * WPB;
    const int nquad = B >> 2;            // 4 rows per wave-iteration

    float acc = 0.f;

    auto load_quad = [&](int q) -> Frag {
        Frag f;
        const size_t base = (size_t)q * 512;   // 4 rows x 128 floats
        const float4* pa = (const float4*)(A + base);
        const float4* pp = (const float4*)(P + base);
        const float4* pn = (const float4*)(N + base);
        f.a0 = pa[lane]; f.a1 = pa[lane + 64];
        f.p0 = pp[lane]; f.p1 = pp[lane + 64];
        f.n0 = pn[lane]; f.n1 = pn[lane + 64];
        return f;
    };

    auto compute = [&](const Frag& f, int q) {
        float d0, d1, d2, d3;
        d0 = f.a0.x - f.p0.x; d1 = f.a0.y - f.p0.y; d2 = f.a0.z - f.p0.z; d3 = f.a0.w - f.p0.w;
        float sap0 = d0*d0 + d1*d1 + d2*d2 + d3*d3;
        d0 = f.a0.x - f.n0.x; d1 = f.a0.y - f.n0.y; d2 = f.a0.z - f.n0.z; d3 = f.a0.w - f.n0.w;
        float san0 = d0*d0 + d1*d1 + d2*d2 + d3*d3;
        d0 = f.a1.x - f.p1.x; d1 = f.a1.y - f.p1.y; d2 = f.a1.z - f.p1.z; d3 = f.a1.w - f.p1.w;
        float sap1 = d0*d0 + d1*d1 + d2*d2 + d3*d3;
        d0 = f.a1.x - f.n1.x; d1 = f.a1.y - f.n1.y; d2 = f.a1.z - f.n1.z; d3 = f.a1.w - f.n1.w;
        float san1 = d0*d0 + d1*d1 + d2*d2 + d3*d3;

        sap0 = reduce32(sap0); san0 = reduce32(san0);
        sap1 = reduce32(sap1); san1 = reduce32(san1);

        if ((lane & 31) == 31) {                  // lanes 31, 63 each finish 2 rows
            const int r0 = q * 4 + (lane >> 5);   // rows 4q, 4q+1
            const int r1 = r0 + 2;                // rows 4q+2, 4q+3
            const int b0 = bidx[r0];
            const int b1 = bidx[r1];
            const float2 t0 = ((const float2*)T)[b0];
            const float2 t1 = ((const float2*)T)[b1];
            const float Dap0 = __expf(-t0.x), Dan0 = __expf(-t0.y);
            const float Dap1 = __expf(-t1.x), Dan1 = __expf(-t1.y);
            const float vap0 = __expf(-sqrtf(sap0)), van0 = __expf(-sqrtf(san0));
            const float vap1 = __expf(-sqrtf(sap1)), van1 = __expf(-sqrtf(san1));
            float e;
            e = Dap0 - vap0; acc += Dap0 * e * e;
            e = Dan0 - van0; acc += Dan0 * e * e;
            e = Dap1 - vap1; acc += Dap1 * e * e;
            e = Dan1 - van1; acc += Dan1 * e * e;
        }
    };

    // Explicit ping-pong software pipeline: next quad's 6 loads issue
    // before the current quad's compute consumes its registers.
    int q = gwave;
    if (q < nquad) {
        Frag fa = load_quad(q);
        for (;;) {
            const int qb = q + nwav;
            if (qb >= nquad) { compute(fa, q); break; }
            Frag fb = load_quad(qb);
            compute(fa, q);
            const int qa = qb + nwav;
            if (qa >= nquad) { compute(fb, qb); break; }
            fa = load_quad(qa);
            compute(fb, qb);
            q = qa;
        }
    }

    // acc lives in lanes 31 and 63 of each wave
    acc += __shfl_xor(acc, 32);
    __shared__ float wacc[WPB];
    if (lane == 31) wacc[wid] = acc;
    __syncthreads();
    if (threadIdx.x == 0) {
        float s = 0.f;
        #pragma unroll
        for (int i = 0; i < WPB; ++i) s += wacc[i];
        atomicAdd(out, s * invB);
    }
}

extern "C" void kernel_launch(void* const* d_in, const int* in_sizes, int n_in,
                              void* d_out, int out_size, void* d_ws, size_t ws_size,
                              hipStream_t stream) {
    const float* A    = (const float*)d_in[0];
    const float* P    = (const float*)d_in[1];
    const float* N    = (const float*)d_in[2];
    const float* T    = (const float*)d_in[3];
    const int*   bidx = (const int*)  d_in[4];

    const int B = in_sizes[0] / 128;
    float* out = (float*)d_out;

    hipMemsetAsync(out, 0, sizeof(float), stream);

    const int blocks = 2048;   // 8 blocks/CU, 8192 waves; 16 quads per wave
    LossFun_kernel<<<blocks, BLOCK, 0, stream>>>(A, P, N, T, bidx, out, B, 1.0f / (float)B);
}